// Round 1
// baseline (484.449 us; speedup 1.0000x reference)
//
#include <hip/hip_runtime.h>
#include <hip/hip_bf16.h>
#include <math.h>

typedef unsigned short u16;
typedef __attribute__((ext_vector_type(8))) short bf16x8;
typedef __attribute__((ext_vector_type(4))) float f32x4;
typedef __attribute__((ext_vector_type(8))) unsigned short u16x8;

#define MFMA16(a, b, c) __builtin_amdgcn_mfma_f32_16x16x32_bf16(a, b, c, 0, 0, 0)

__device__ __forceinline__ u16 f2bf(float f) {
  union { float f; unsigned u; } v; v.f = f;
  unsigned r = v.u + 0x7FFFu + ((v.u >> 16) & 1u);
  return (u16)(r >> 16);
}
__device__ __forceinline__ float bf2f(u16 h) {
  union { unsigned u; float f; } v; v.u = ((unsigned)h) << 16;
  return v.f;
}

__device__ __forceinline__ void gload_lds16(const void* g, void* l) {
  __builtin_amdgcn_global_load_lds((__attribute__((address_space(1))) void*)g,
                                   (__attribute__((address_space(3))) void*)l, 16, 0, 0);
}

// ---------------- cast fp32 -> bf16 ----------------
__global__ void cast_f32_bf16(const float* __restrict__ in, u16* __restrict__ out, int n4) {
  int i = blockIdx.x * blockDim.x + threadIdx.x;
  int stride = gridDim.x * blockDim.x;
  for (; i < n4; i += stride) {
    float4 v = ((const float4*)in)[i];
    u16x8 dummy; (void)dummy;
    u16 r0 = f2bf(v.x), r1 = f2bf(v.y), r2 = f2bf(v.z), r3 = f2bf(v.w);
    unsigned lo = (unsigned)r0 | ((unsigned)r1 << 16);
    unsigned hi = (unsigned)r2 | ((unsigned)r3 << 16);
    ((uint2*)out)[i] = make_uint2(lo, hi);
  }
}

// ---------------- RoPE tables (double precision on device) ----------------
// tab[0 .. 131071] = cos, tab[131072 .. 262143] = sin ; index = s*64 + j
__global__ void rope_table(float* __restrict__ tab) {
  int idx = blockIdx.x * 256 + threadIdx.x;   // 131072 total
  int s = idx >> 6, j = idx & 63;
  double ang = (double)s * pow(10000.0, -(double)j / 64.0);
  tab[idx] = (float)cos(ang);
  tab[131072 + idx] = (float)sin(ang);
}

// ---------------- RoPE apply (in place, bf16), rotate-half ----------------
// x layout: [B*H*S][128]; one thread per (row, j<64)
__global__ void rope_apply(u16* __restrict__ x, const float* __restrict__ tab, float scale) {
  int idx = blockIdx.x * 256 + threadIdx.x;   // 2*16*2048*64 = 4194304 total
  int r = idx >> 6, j = idx & 63;
  int s = r & 2047;
  float c = tab[s * 64 + j];
  float sn = tab[131072 + s * 64 + j];
  u16* p = x + (long)r * 128;
  float x1 = bf2f(p[j]);
  float x2 = bf2f(p[j + 64]);
  p[j]      = f2bf((x1 * c - x2 * sn) * scale);
  p[j + 64] = f2bf((x2 * c + x1 * sn) * scale);
}

// ---------------- V transpose: [bh][s][d] -> [bh][d][s] ----------------
__global__ __launch_bounds__(256) void transpose_v(const u16* __restrict__ v, u16* __restrict__ vt) {
  __shared__ __align__(16) u16 tile[64][72];
  int s0 = blockIdx.x * 64, d0 = blockIdx.y * 64, bh = blockIdx.z;
  int t = threadIdx.x;
  const long base = (long)bh * 2048 * 128;
#pragma unroll
  for (int it = 0; it < 2; ++it) {
    int idx = it * 256 + t;          // 512 chunks of 16B
    int r = idx >> 3, c = idx & 7;   // r: s-row, c: d-chunk
    *(u16x8*)&tile[r][c * 8] = *(const u16x8*)(v + base + (long)(s0 + r) * 128 + d0 + c * 8);
  }
  __syncthreads();
  const long obase = (long)bh * 128 * 2048;
#pragma unroll
  for (int it = 0; it < 2; ++it) {
    int idx = it * 256 + t;
    int rd = idx >> 3, cs = idx & 7; // rd: d-row, cs: s-chunk
    u16x8 o;
#pragma unroll
    for (int i = 0; i < 8; ++i) o[i] = tile[cs * 8 + i][rd];
    *(u16x8*)(vt + obase + (long)(d0 + rd) * 2048 + s0 + cs * 8) = o;
  }
}

// ---------------- GEMM: C[M,N] = A[M,K] * Bw[N,K]^T (both bf16, K-major) ----------
// EPI 0: fp32 row-major C. EPI 1: bf16 scatter into qkv [3][B=2][H=16][S=2048][128].
template<int EPI>
__global__ __launch_bounds__(256) void gemm_bt(const u16* __restrict__ A, const u16* __restrict__ Bw,
                                               void* __restrict__ C, int M, int N, int K) {
  __shared__ __align__(16) u16 As[128 * 32];
  __shared__ __align__(16) u16 Bs[128 * 32];
  const int t = threadIdx.x;
  const int w = t >> 6, l = t & 63;
  const int lr = l & 15, lg = l >> 4;
  const int m0 = blockIdx.x * 128, n0 = blockIdx.y * 128;
  const int wr = w >> 1, wc = w & 1;   // 2x2 waves, each 64x64 output
  f32x4 acc[4][4];
#pragma unroll
  for (int i = 0; i < 4; ++i)
#pragma unroll
    for (int j = 0; j < 4; ++j)
#pragma unroll
      for (int e = 0; e < 4; ++e) acc[i][j][e] = 0.f;

  for (int kt = 0; kt < K; kt += 32) {
    __syncthreads();
#pragma unroll
    for (int it = 0; it < 2; ++it) {
      int idx = it * 256 + t;          // 512 chunks of 16B per 8KB tile
      int wb = it * 256 + w * 64;      // wave-uniform chunk base
      const u16* ga = A + (long)(m0 + (idx >> 2)) * K + kt + (idx & 3) * 8;
      gload_lds16(ga, As + (long)wb * 8);
      const u16* gb = Bw + (long)(n0 + (idx >> 2)) * K + kt + (idx & 3) * 8;
      gload_lds16(gb, Bs + (long)wb * 8);
    }
    __syncthreads();
    bf16x8 af[4], bfr[4];
#pragma unroll
    for (int mr = 0; mr < 4; ++mr) af[mr] = *(const bf16x8*)&As[(wr * 64 + mr * 16 + lr) * 32 + lg * 8];
#pragma unroll
    for (int nr = 0; nr < 4; ++nr) bfr[nr] = *(const bf16x8*)&Bs[(wc * 64 + nr * 16 + lr) * 32 + lg * 8];
#pragma unroll
    for (int mr = 0; mr < 4; ++mr)
#pragma unroll
      for (int nr = 0; nr < 4; ++nr)
        acc[mr][nr] = MFMA16(af[mr], bfr[nr], acc[mr][nr]);
  }

  if (EPI == 0) {
    float* Co = (float*)C;
#pragma unroll
    for (int mr = 0; mr < 4; ++mr)
#pragma unroll
      for (int nr = 0; nr < 4; ++nr)
#pragma unroll
        for (int j = 0; j < 4; ++j) {
          int row = m0 + wr * 64 + mr * 16 + lg * 4 + j;
          int col = n0 + wc * 64 + nr * 16 + lr;
          Co[(long)row * N + col] = acc[mr][nr][j];
        }
  } else {
    u16* Q = (u16*)C;
    const long PART = 8388608L;  // 2*16*2048*128
#pragma unroll
    for (int mr = 0; mr < 4; ++mr)
#pragma unroll
      for (int nr = 0; nr < 4; ++nr)
#pragma unroll
        for (int j = 0; j < 4; ++j) {
          int row = m0 + wr * 64 + mr * 16 + lg * 4 + j;   // b*2048 + s
          int col = n0 + wc * 64 + nr * 16 + lr;           // part*2048 + h*128 + d
          int part = col >> 11, h = (col >> 7) & 15, d = col & 127;
          int b = row >> 11, s = row & 2047;
          Q[part * PART + ((long)((b * 16 + h) * 2048 + s)) * 128 + d] = f2bf(acc[mr][nr][j]);
        }
  }
}

// ---------------- Flash attention (causal), QB=KB=64, 4 waves ----------------
// q,k: [bh][s][128] bf16 (q pre-scaled); vt: [bh][d][s]; ctx out: [b][s][h*128+d] bf16
__global__ __launch_bounds__(256) void flash_fwd(const u16* __restrict__ qg, const u16* __restrict__ kg,
                                                 const u16* __restrict__ vtg, u16* __restrict__ ctx) {
  const int qi = blockIdx.x, bh = blockIdx.y;
  const int t = threadIdx.x, w = t >> 6, l = t & 63;
  const int lr = l & 15, lg = l >> 4;
  const int q0 = qi * 64;
  const long skbase = (long)bh * 2048 * 128;
  const long vtbase = (long)bh * 128 * 2048;
  __shared__ __align__(16) u16 Kl[64][136];   // [kv][d], stride 272B (17*16)
  __shared__ __align__(16) u16 Vl[128][72];   // [d][kv], stride 144B (9*16)
  __shared__ __align__(16) u16 Pl[4][16][72]; // per-wave P [q][kv]

  bf16x8 qf[4];
  {
    const u16* qrow = qg + skbase + (long)(q0 + w * 16 + lr) * 128;
#pragma unroll
    for (int dc = 0; dc < 4; ++dc) qf[dc] = *(const bf16x8*)(qrow + dc * 32 + lg * 8);
  }
  f32x4 acc[8];
#pragma unroll
  for (int dc = 0; dc < 8; ++dc)
#pragma unroll
    for (int e = 0; e < 4; ++e) acc[dc][e] = 0.f;
  float mrow[4] = {-1e30f, -1e30f, -1e30f, -1e30f};
  float lsum[4] = {0.f, 0.f, 0.f, 0.f};

  for (int kvt = 0; kvt <= qi; ++kvt) {
    const int kv0 = kvt * 64;
    __syncthreads();
#pragma unroll
    for (int it = 0; it < 4; ++it) {       // K tile: 64 rows x 16 chunks
      int idx = it * 256 + t;
      int r = idx >> 4, c = idx & 15;
      *(u16x8*)&Kl[r][c * 8] = *(const u16x8*)(kg + skbase + (long)(kv0 + r) * 128 + c * 8);
    }
#pragma unroll
    for (int it = 0; it < 4; ++it) {       // Vt tile: 128 rows x 8 chunks
      int idx = it * 256 + t;
      int r = idx >> 3, c = idx & 7;
      *(u16x8*)&Vl[r][c * 8] = *(const u16x8*)(vtg + vtbase + (long)r * 2048 + kv0 + c * 8);
    }
    __syncthreads();

    f32x4 sc[4];
#pragma unroll
    for (int c = 0; c < 4; ++c)
#pragma unroll
      for (int e = 0; e < 4; ++e) sc[c][e] = 0.f;
#pragma unroll
    for (int dc = 0; dc < 4; ++dc)
#pragma unroll
      for (int c = 0; c < 4; ++c) {
        bf16x8 kf = *(const bf16x8*)&Kl[c * 16 + lr][dc * 32 + lg * 8];
        sc[c] = MFMA16(qf[dc], kf, sc[c]);
      }

    if (kvt == qi) {
#pragma unroll
      for (int c = 0; c < 4; ++c)
#pragma unroll
        for (int j = 0; j < 4; ++j) {
          int kvi = kv0 + c * 16 + lr;
          int qq = q0 + w * 16 + lg * 4 + j;
          if (kvi > qq) sc[c][j] = -1e30f;
        }
    }

    float pmax[4];
#pragma unroll
    for (int j = 0; j < 4; ++j)
      pmax[j] = fmaxf(fmaxf(sc[0][j], sc[1][j]), fmaxf(sc[2][j], sc[3][j]));
#pragma unroll
    for (int off = 8; off >= 1; off >>= 1)
#pragma unroll
      for (int j = 0; j < 4; ++j)
        pmax[j] = fmaxf(pmax[j], __shfl_xor(pmax[j], off));
    float alpha[4];
#pragma unroll
    for (int j = 0; j < 4; ++j) {
      float mn = fmaxf(mrow[j], pmax[j]);
      alpha[j] = __expf(mrow[j] - mn);
      mrow[j] = mn;
    }
    float rs[4] = {0.f, 0.f, 0.f, 0.f};
#pragma unroll
    for (int c = 0; c < 4; ++c)
#pragma unroll
      for (int j = 0; j < 4; ++j) {
        float p = __expf(sc[c][j] - mrow[j]);
        sc[c][j] = p;
        rs[j] += p;
      }
#pragma unroll
    for (int off = 8; off >= 1; off >>= 1)
#pragma unroll
      for (int j = 0; j < 4; ++j)
        rs[j] += __shfl_xor(rs[j], off);
#pragma unroll
    for (int j = 0; j < 4; ++j) lsum[j] = lsum[j] * alpha[j] + rs[j];
#pragma unroll
    for (int dc = 0; dc < 8; ++dc)
#pragma unroll
      for (int j = 0; j < 4; ++j) acc[dc][j] *= alpha[j];

#pragma unroll
    for (int c = 0; c < 4; ++c)
#pragma unroll
      for (int j = 0; j < 4; ++j)
        Pl[w][lg * 4 + j][c * 16 + lr] = f2bf(sc[c][j]);

#pragma unroll
    for (int kc = 0; kc < 2; ++kc) {
      bf16x8 pa = *(const bf16x8*)&Pl[w][lr][kc * 32 + lg * 8];
#pragma unroll
      for (int dc = 0; dc < 8; ++dc) {
        bf16x8 vb = *(const bf16x8*)&Vl[dc * 16 + lr][kc * 32 + lg * 8];
        acc[dc] = MFMA16(pa, vb, acc[dc]);
      }
    }
  }

  const int b = bh >> 4, h = bh & 15;
#pragma unroll
  for (int j = 0; j < 4; ++j) {
    float inv = 1.f / lsum[j];
    int s = q0 + w * 16 + lg * 4 + j;
    u16* orow = ctx + ((long)(b * 2048 + s)) * 2048 + h * 128;
#pragma unroll
    for (int dc = 0; dc < 8; ++dc)
      orow[dc * 16 + lr] = f2bf(acc[dc][j] * inv);
  }
}

// ---------------- launch ----------------
extern "C" void kernel_launch(void* const* d_in, const int* in_sizes, int n_in,
                              void* d_out, int out_size, void* d_ws, size_t ws_size,
                              hipStream_t stream) {
  const float* x = (const float*)d_in[0];
  const float* wqkv = (const float*)d_in[1];
  const float* wproj = (const float*)d_in[2];
  float* out = (float*)d_out;

  u16* xb   = (u16*)d_ws;             // 8,388,608 elems
  u16* wqb  = xb + 8388608;           // 12,582,912
  u16* wpb  = wqb + 12582912;         // 4,194,304
  u16* qkv  = wpb + 4194304;          // 25,165,824 (q | k | v, each 8,388,608)
  u16* vt   = qkv + 25165824;         // 8,388,608
  u16* ctx  = vt + 8388608;           // 8,388,608
  float* tab = (float*)(ctx + 8388608); // 262,144 floats (1 MB)

  cast_f32_bf16<<<2048, 256, 0, stream>>>(x, xb, 8388608 / 4);
  cast_f32_bf16<<<2048, 256, 0, stream>>>(wqkv, wqb, 12582912 / 4);
  cast_f32_bf16<<<1024, 256, 0, stream>>>(wproj, wpb, 4194304 / 4);
  rope_table<<<512, 256, 0, stream>>>(tab);

  // QKV projection: [4096,2048] x [6144,2048]^T, scatter epilogue into q/k/v
  gemm_bt<1><<<dim3(32, 48), 256, 0, stream>>>(xb, wqb, qkv, 4096, 6144, 2048);

  // RoPE in place; fold 1/sqrt(128) into q
  rope_apply<<<16384, 256, 0, stream>>>(qkv, tab, 0.08838834764831845f);
  rope_apply<<<16384, 256, 0, stream>>>(qkv + 8388608, tab, 1.0f);

  transpose_v<<<dim3(32, 2, 32), 256, 0, stream>>>(qkv + 16777216, vt);

  flash_fwd<<<dim3(32, 32), 256, 0, stream>>>(qkv, qkv + 8388608, vt, ctx);

  // Output projection -> fp32 d_out
  gemm_bt<0><<<dim3(32, 16), 256, 0, stream>>>(ctx, wpb, out, 4096, 2048, 2048);
}

// Round 2
// 335.041 us; speedup vs baseline: 1.4459x; 1.4459x over previous
//
#include <hip/hip_runtime.h>
#include <hip/hip_bf16.h>
#include <math.h>

typedef unsigned short u16;
typedef __attribute__((ext_vector_type(8))) short bf16x8;
typedef __attribute__((ext_vector_type(4))) float f32x4;
typedef __attribute__((ext_vector_type(8))) unsigned short u16x8;

#define MFMA16(a, b, c) __builtin_amdgcn_mfma_f32_16x16x32_bf16(a, b, c, 0, 0, 0)

__device__ __forceinline__ u16 f2bf(float f) {
  union { float f; unsigned u; } v; v.f = f;
  unsigned r = v.u + 0x7FFFu + ((v.u >> 16) & 1u);
  return (u16)(r >> 16);
}
__device__ __forceinline__ float bf2f(u16 h) {
  union { unsigned u; float f; } v; v.u = ((unsigned)h) << 16;
  return v.f;
}

__device__ __forceinline__ void gload_lds16(const void* g, void* l) {
  __builtin_amdgcn_global_load_lds((__attribute__((address_space(1))) void*)g,
                                   (__attribute__((address_space(3))) void*)l, 16, 0, 0);
}

// ---------------- cast fp32 -> bf16 ----------------
__global__ void cast_f32_bf16(const float* __restrict__ in, u16* __restrict__ out, int n4) {
  int i = blockIdx.x * blockDim.x + threadIdx.x;
  int stride = gridDim.x * blockDim.x;
  for (; i < n4; i += stride) {
    float4 v = ((const float4*)in)[i];
    u16 r0 = f2bf(v.x), r1 = f2bf(v.y), r2 = f2bf(v.z), r3 = f2bf(v.w);
    unsigned lo = (unsigned)r0 | ((unsigned)r1 << 16);
    unsigned hi = (unsigned)r2 | ((unsigned)r3 << 16);
    ((uint2*)out)[i] = make_uint2(lo, hi);
  }
}

// ---------------- RoPE tables (double precision on device) ----------------
// tab[0 .. 131071] = cos, tab[131072 .. 262143] = sin ; index = s*64 + j
__global__ void rope_table(float* __restrict__ tab) {
  int idx = blockIdx.x * 256 + threadIdx.x;   // 131072 total
  int s = idx >> 6, j = idx & 63;
  double ang = (double)s * pow(10000.0, -(double)j / 64.0);
  tab[idx] = (float)cos(ang);
  tab[131072 + idx] = (float)sin(ang);
}

// ---------------- RoPE apply (in place, bf16), rotate-half ----------------
// x layout: [B*H*S][128]; one thread per (row, j<64)
__global__ void rope_apply(u16* __restrict__ x, const float* __restrict__ tab, float scale) {
  int idx = blockIdx.x * 256 + threadIdx.x;   // 2*16*2048*64 = 4194304 total
  int r = idx >> 6, j = idx & 63;
  int s = r & 2047;
  float c = tab[s * 64 + j];
  float sn = tab[131072 + s * 64 + j];
  u16* p = x + (long)r * 128;
  float x1 = bf2f(p[j]);
  float x2 = bf2f(p[j + 64]);
  p[j]      = f2bf((x1 * c - x2 * sn) * scale);
  p[j + 64] = f2bf((x2 * c + x1 * sn) * scale);
}

// ---------------- V transpose: [bh][s][d] -> [bh][d][s] ----------------
__global__ __launch_bounds__(256) void transpose_v(const u16* __restrict__ v, u16* __restrict__ vt) {
  __shared__ __align__(16) u16 tile[64][72];
  int s0 = blockIdx.x * 64, d0 = blockIdx.y * 64, bh = blockIdx.z;
  int t = threadIdx.x;
  const long base = (long)bh * 2048 * 128;
#pragma unroll
  for (int it = 0; it < 2; ++it) {
    int idx = it * 256 + t;          // 512 chunks of 16B
    int r = idx >> 3, c = idx & 7;   // r: s-row, c: d-chunk
    *(u16x8*)&tile[r][c * 8] = *(const u16x8*)(v + base + (long)(s0 + r) * 128 + d0 + c * 8);
  }
  __syncthreads();
  const long obase = (long)bh * 128 * 2048;
#pragma unroll
  for (int it = 0; it < 2; ++it) {
    int idx = it * 256 + t;
    int rd = idx >> 3, cs = idx & 7; // rd: d-row, cs: s-chunk
    u16x8 o;
#pragma unroll
    for (int i = 0; i < 8; ++i) o[i] = tile[cs * 8 + i][rd];
    *(u16x8*)(vt + obase + (long)(d0 + rd) * 2048 + s0 + cs * 8) = o;
  }
}

// ---------------- GEMM: C[M,N] = A[M,K] * Bw[N,K]^T (both bf16, K-major) ----------
// EPI 0: fp32 row-major C. EPI 1: bf16 scatter into qkv [3][B=2][H=16][S=2048][128].
template<int EPI>
__global__ __launch_bounds__(256) void gemm_bt(const u16* __restrict__ A, const u16* __restrict__ Bw,
                                               void* __restrict__ C, int M, int N, int K) {
  __shared__ __align__(16) u16 As[128 * 32];
  __shared__ __align__(16) u16 Bs[128 * 32];
  const int t = threadIdx.x;
  const int w = t >> 6, l = t & 63;
  const int lr = l & 15, lg = l >> 4;
  const int m0 = blockIdx.x * 128, n0 = blockIdx.y * 128;
  const int wr = w >> 1, wc = w & 1;   // 2x2 waves, each 64x64 output
  f32x4 acc[4][4];
#pragma unroll
  for (int i = 0; i < 4; ++i)
#pragma unroll
    for (int j = 0; j < 4; ++j)
#pragma unroll
      for (int e = 0; e < 4; ++e) acc[i][j][e] = 0.f;

  for (int kt = 0; kt < K; kt += 32) {
    __syncthreads();
#pragma unroll
    for (int it = 0; it < 2; ++it) {
      int idx = it * 256 + t;          // 512 chunks of 16B per 8KB tile
      int wb = it * 256 + w * 64;      // wave-uniform chunk base
      const u16* ga = A + (long)(m0 + (idx >> 2)) * K + kt + (idx & 3) * 8;
      gload_lds16(ga, As + (long)wb * 8);
      const u16* gb = Bw + (long)(n0 + (idx >> 2)) * K + kt + (idx & 3) * 8;
      gload_lds16(gb, Bs + (long)wb * 8);
    }
    __syncthreads();
    bf16x8 af[4], bfr[4];
#pragma unroll
    for (int mr = 0; mr < 4; ++mr) af[mr] = *(const bf16x8*)&As[(wr * 64 + mr * 16 + lr) * 32 + lg * 8];
#pragma unroll
    for (int nr = 0; nr < 4; ++nr) bfr[nr] = *(const bf16x8*)&Bs[(wc * 64 + nr * 16 + lr) * 32 + lg * 8];
#pragma unroll
    for (int mr = 0; mr < 4; ++mr)
#pragma unroll
      for (int nr = 0; nr < 4; ++nr)
        acc[mr][nr] = MFMA16(af[mr], bfr[nr], acc[mr][nr]);
  }

  if (EPI == 0) {
    float* Co = (float*)C;
#pragma unroll
    for (int mr = 0; mr < 4; ++mr)
#pragma unroll
      for (int nr = 0; nr < 4; ++nr)
#pragma unroll
        for (int j = 0; j < 4; ++j) {
          int row = m0 + wr * 64 + mr * 16 + lg * 4 + j;
          int col = n0 + wc * 64 + nr * 16 + lr;
          Co[(long)row * N + col] = acc[mr][nr][j];
        }
  } else {
    u16* Q = (u16*)C;
    const long PART = 8388608L;  // 2*16*2048*128
#pragma unroll
    for (int mr = 0; mr < 4; ++mr)
#pragma unroll
      for (int nr = 0; nr < 4; ++nr)
#pragma unroll
        for (int j = 0; j < 4; ++j) {
          int row = m0 + wr * 64 + mr * 16 + lg * 4 + j;   // b*2048 + s
          int col = n0 + wc * 64 + nr * 16 + lr;           // part*2048 + h*128 + d
          int part = col >> 11, h = (col >> 7) & 15, d = col & 127;
          int b = row >> 11, s = row & 2047;
          Q[part * PART + ((long)((b * 16 + h) * 2048 + s)) * 128 + d] = f2bf(acc[mr][nr][j]);
        }
  }
}

// ---------------- Flash attention (causal), QB=KB=64, 4 waves ----------------
// q,k: [bh][s][128] bf16 (q pre-scaled by 1/sqrt(d)*log2e); vt: [bh][d][s];
// ctx out: [b][s][h*128+d] bf16.
// Block mapping: bid&7 = XCD slot (owns 4 bh -> K/V 4MB = one L2);
// qi descending within slot (longest blocks first).
__global__ __launch_bounds__(256, 3) void flash_fwd(const u16* __restrict__ qg, const u16* __restrict__ kg,
                                                    const u16* __restrict__ vtg, u16* __restrict__ ctx) {
  const int bid = blockIdx.x;
  const int xcd = bid & 7;
  const int seq = bid >> 3;              // 0..127
  const int bh = xcd * 4 + (seq & 3);    // 0..31
  const int qi = 31 - (seq >> 2);        // 0..31, descending
  const int t = threadIdx.x, w = t >> 6, l = t & 63;
  const int lr = l & 15, lg = l >> 4;
  const int q0 = qi * 64;
  const int nkv = qi + 1;
  const long skbase = (long)bh * 2048 * 128;
  const long vtbase = (long)bh * 128 * 2048;
  __shared__ __align__(16) u16 Kl[64][136];   // [kv][d], stride 272B
  __shared__ __align__(16) u16 Vl[128][72];   // [d][kv], stride 144B
  __shared__ __align__(16) u16 Pl[4][16][72]; // per-wave P [q][kv]

  bf16x8 qf[4];
  {
    const u16* qrow = qg + skbase + (long)(q0 + w * 16 + lr) * 128;
#pragma unroll
    for (int dc = 0; dc < 4; ++dc) qf[dc] = *(const bf16x8*)(qrow + dc * 32 + lg * 8);
  }
  f32x4 acc[8];
#pragma unroll
  for (int dc = 0; dc < 8; ++dc)
#pragma unroll
    for (int e = 0; e < 4; ++e) acc[dc][e] = 0.f;
  float mrow[4] = {-1e30f, -1e30f, -1e30f, -1e30f};
  float lsum[4] = {0.f, 0.f, 0.f, 0.f};

  // staging pointers: thread t handles K chunks (it*16 + t>>4, t&15), V chunks (it*32 + t>>3, t&7)
  const u16* kga = kg + skbase + (long)(t >> 4) * 128 + (t & 15) * 8;
  const u16* vga = vtg + vtbase + (long)(t >> 3) * 2048 + (t & 7) * 8;
  u16* klp = &Kl[t >> 4][(t & 15) * 8];
  u16* vlp = &Vl[t >> 3][(t & 7) * 8];

  u16x8 rk[4], rv[4];
#pragma unroll
  for (int it = 0; it < 4; ++it) {
    rk[it] = *(const u16x8*)(kga + it * 2048);
    rv[it] = *(const u16x8*)(vga + it * 65536);
  }

  for (int kvt = 0; kvt < nkv; ++kvt) {
    __syncthreads();                     // all waves done reading previous tile
#pragma unroll
    for (int it = 0; it < 4; ++it) {     // regs -> LDS (waits vmcnt internally)
      *(u16x8*)(klp + it * 16 * 136) = rk[it];
      *(u16x8*)(vlp + it * 32 * 72) = rv[it];
    }
    __syncthreads();                     // LDS tile ready
    if (kvt + 1 < nkv) {                 // prefetch next tile -> regs (covered by compute)
      const u16* ka = kga + (long)(kvt + 1) * 8192;
      const u16* va = vga + (long)(kvt + 1) * 64;
#pragma unroll
      for (int it = 0; it < 4; ++it) {
        rk[it] = *(const u16x8*)(ka + it * 2048);
        rv[it] = *(const u16x8*)(va + it * 65536);
      }
    }

    const int kv0 = kvt * 64;
    f32x4 sc[4];
#pragma unroll
    for (int c = 0; c < 4; ++c)
#pragma unroll
      for (int e = 0; e < 4; ++e) sc[c][e] = 0.f;
#pragma unroll
    for (int dc = 0; dc < 4; ++dc)
#pragma unroll
      for (int c = 0; c < 4; ++c) {
        bf16x8 kf = *(const bf16x8*)&Kl[c * 16 + lr][dc * 32 + lg * 8];
        sc[c] = MFMA16(qf[dc], kf, sc[c]);
      }

    if (kvt == qi) {
#pragma unroll
      for (int c = 0; c < 4; ++c)
#pragma unroll
        for (int j = 0; j < 4; ++j) {
          int kvi = kv0 + c * 16 + lr;
          int qq = q0 + w * 16 + lg * 4 + j;
          if (kvi > qq) sc[c][j] = -1e30f;
        }
    }

    float pmax[4];
#pragma unroll
    for (int j = 0; j < 4; ++j)
      pmax[j] = fmaxf(fmaxf(sc[0][j], sc[1][j]), fmaxf(sc[2][j], sc[3][j]));
#pragma unroll
    for (int off = 8; off >= 1; off >>= 1)
#pragma unroll
      for (int j = 0; j < 4; ++j)
        pmax[j] = fmaxf(pmax[j], __shfl_xor(pmax[j], off));

    // T13 defer-max: only rescale when max grew by > 8 (log2 domain)
    int skip = __all(pmax[0] <= mrow[0] + 8.f && pmax[1] <= mrow[1] + 8.f &&
                     pmax[2] <= mrow[2] + 8.f && pmax[3] <= mrow[3] + 8.f);
    if (!skip) {
#pragma unroll
      for (int j = 0; j < 4; ++j) {
        float mn = fmaxf(mrow[j], pmax[j]);
        float alpha = __builtin_amdgcn_exp2f(mrow[j] - mn);
        mrow[j] = mn;
        lsum[j] *= alpha;
#pragma unroll
        for (int dc = 0; dc < 8; ++dc) acc[dc][j] *= alpha;
      }
    }

    float rs[4] = {0.f, 0.f, 0.f, 0.f};
#pragma unroll
    for (int c = 0; c < 4; ++c)
#pragma unroll
      for (int j = 0; j < 4; ++j) {
        float p = __builtin_amdgcn_exp2f(sc[c][j] - mrow[j]);
        sc[c][j] = p;
        rs[j] += p;
      }
#pragma unroll
    for (int off = 8; off >= 1; off >>= 1)
#pragma unroll
      for (int j = 0; j < 4; ++j)
        rs[j] += __shfl_xor(rs[j], off);
#pragma unroll
    for (int j = 0; j < 4; ++j) lsum[j] += rs[j];

#pragma unroll
    for (int c = 0; c < 4; ++c)
#pragma unroll
      for (int j = 0; j < 4; ++j)
        Pl[w][lg * 4 + j][c * 16 + lr] = f2bf(sc[c][j]);

#pragma unroll
    for (int kc = 0; kc < 2; ++kc) {
      bf16x8 pa = *(const bf16x8*)&Pl[w][lr][kc * 32 + lg * 8];
#pragma unroll
      for (int dc = 0; dc < 8; ++dc) {
        bf16x8 vb = *(const bf16x8*)&Vl[dc * 16 + lr][kc * 32 + lg * 8];
        acc[dc] = MFMA16(pa, vb, acc[dc]);
      }
    }
  }

  const int b = bh >> 4, h = bh & 15;
#pragma unroll
  for (int j = 0; j < 4; ++j) {
    float inv = 1.f / lsum[j];
    int s = q0 + w * 16 + lg * 4 + j;
    u16* orow = ctx + ((long)(b * 2048 + s)) * 2048 + h * 128;
#pragma unroll
    for (int dc = 0; dc < 8; ++dc)
      orow[dc * 16 + lr] = f2bf(acc[dc][j] * inv);
  }
}

// ---------------- launch ----------------
extern "C" void kernel_launch(void* const* d_in, const int* in_sizes, int n_in,
                              void* d_out, int out_size, void* d_ws, size_t ws_size,
                              hipStream_t stream) {
  const float* x = (const float*)d_in[0];
  const float* wqkv = (const float*)d_in[1];
  const float* wproj = (const float*)d_in[2];
  float* out = (float*)d_out;

  u16* xb   = (u16*)d_ws;             // 8,388,608 elems
  u16* wqb  = xb + 8388608;           // 12,582,912
  u16* wpb  = wqb + 12582912;         // 4,194,304
  u16* qkv  = wpb + 4194304;          // 25,165,824 (q | k | v, each 8,388,608)
  u16* vt   = qkv + 25165824;         // 8,388,608
  u16* ctx  = vt + 8388608;           // 8,388,608
  float* tab = (float*)(ctx + 8388608); // 262,144 floats (1 MB)

  cast_f32_bf16<<<2048, 256, 0, stream>>>(x, xb, 8388608 / 4);
  cast_f32_bf16<<<2048, 256, 0, stream>>>(wqkv, wqb, 12582912 / 4);
  cast_f32_bf16<<<1024, 256, 0, stream>>>(wproj, wpb, 4194304 / 4);
  rope_table<<<512, 256, 0, stream>>>(tab);

  // QKV projection: [4096,2048] x [6144,2048]^T, scatter epilogue into q/k/v
  gemm_bt<1><<<dim3(32, 48), 256, 0, stream>>>(xb, wqb, qkv, 4096, 6144, 2048);

  // RoPE in place; fold 1/sqrt(128)*log2(e) into q (softmax runs in exp2 domain)
  rope_apply<<<16384, 256, 0, stream>>>(qkv, tab, 0.12751744906275268f);
  rope_apply<<<16384, 256, 0, stream>>>(qkv + 8388608, tab, 1.0f);

  transpose_v<<<dim3(32, 2, 32), 256, 0, stream>>>(qkv + 16777216, vt);

  flash_fwd<<<1024, 256, 0, stream>>>(qkv, qkv + 8388608, vt, ctx);

  // Output projection -> fp32 d_out
  gemm_bt<0><<<dim3(32, 16), 256, 0, stream>>>(ctx, wpb, out, 4096, 2048, 2048);
}